// Round 1
// baseline (11999.451 us; speedup 1.0000x reference)
//
#include <hip/hip_runtime.h>
#include <math.h>

#define BB 64
#define RR 1024
#define TT 200
#define HH 512
#define VV 1000
#define GG 2048

__device__ __forceinline__ float sigmf(float x) { return 1.f / (1.f + __expf(-x)); }

// ---------------- transpose: dst[n][m] = src[m*sstride + soff + n] ----------------
__global__ __launch_bounds__(256) void transpose_k(const float* __restrict__ src,
    float* __restrict__ dst, int Msrc, int Mdst, int N, int sstride, int soff) {
  __shared__ float tile[32][33];
  int mt = blockIdx.y * 32, ntb = blockIdx.x * 32;
  int tx = threadIdx.x & 31, ty = threadIdx.x >> 5;
  #pragma unroll
  for (int i = ty; i < 32; i += 8) {
    int m = mt + i, n = ntb + tx;
    tile[i][tx] = (m < Msrc && n < N) ? src[(size_t)m * sstride + soff + n] : 0.f;
  }
  __syncthreads();
  #pragma unroll
  for (int i = ty; i < 32; i += 8) {
    int n = ntb + i, m = mt + tx;
    if (n < N && m < Mdst) dst[(size_t)n * Mdst + m] = tile[tx][i];
  }
}

// ---------------- big GEMM: C[M][cld] = A[M][512] @ W[512][wld-slab] + bias ----------------
// BM=128, BN=64, BK=16, 256 threads, 8x4 per thread. Grid covers M,N exactly (pad via guards on store).
__global__ __launch_bounds__(256) void biggemm_k(const float* __restrict__ A,
    const float* __restrict__ W, int wld, const float* __restrict__ bias,
    float* __restrict__ C, int cld, int Nout) {
  int mt = blockIdx.x * 128, nt = blockIdx.y * 64;
  __shared__ float As[16][132];
  __shared__ float Ws[16][68];
  int tid = threadIdx.x;
  int ty = tid >> 4, tx = tid & 15;
  float acc[8][4] = {};
  for (int k0 = 0; k0 < 512; k0 += 16) {
    {
      int kc = (tid & 3) * 4;
      int r0 = tid >> 2;
      #pragma unroll
      for (int hh = 0; hh < 2; hh++) {
        int row = r0 + hh * 64;
        float4 a4 = *(const float4*)&A[(size_t)(mt + row) * 512 + k0 + kc];
        As[kc + 0][row] = a4.x; As[kc + 1][row] = a4.y;
        As[kc + 2][row] = a4.z; As[kc + 3][row] = a4.w;
      }
      int krow = tid >> 4, nc = (tid & 15) * 4;
      *(float4*)&Ws[krow][nc] = *(const float4*)&W[(size_t)(k0 + krow) * wld + nt + nc];
    }
    __syncthreads();
    #pragma unroll
    for (int kk = 0; kk < 16; kk++) {
      float4 a0 = *(float4*)&As[kk][ty * 8];
      float4 a1 = *(float4*)&As[kk][ty * 8 + 4];
      float4 w4 = *(float4*)&Ws[kk][tx * 4];
      float av[8] = {a0.x, a0.y, a0.z, a0.w, a1.x, a1.y, a1.z, a1.w};
      float wv[4] = {w4.x, w4.y, w4.z, w4.w};
      #pragma unroll
      for (int i = 0; i < 8; i++)
        #pragma unroll
        for (int j = 0; j < 4; j++)
          acc[i][j] += av[i] * wv[j];
    }
    __syncthreads();
  }
  #pragma unroll
  for (int i = 0; i < 8; i++) {
    int m = mt + ty * 8 + i;
    #pragma unroll
    for (int j = 0; j < 4; j++) {
      int n = nt + tx * 4 + j;
      if (n < Nout) C[(size_t)m * cld + n] = acc[i][j] + bias[n];
    }
  }
}

// ---------------- small GEMM: Cpart[kc][64][N] = A[64][k0:k0+128] @ W[k0:,:N-slab] ----------------
// grid.x = N/64 tiles, grid.y = kchunks (4 single / 8 dual). Direct (deterministic) partial writes.
__global__ __launch_bounds__(256) void smallgemm_k(
    const float* __restrict__ A1, const float* __restrict__ W1, int wld1,
    const float* __restrict__ A2, const float* __restrict__ W2, int wld2,
    int dual, float* __restrict__ Cpart, int N) {
  int nt = blockIdx.x, kc = blockIdx.y;
  const float *A, *W; int wld, k0;
  if (dual && kc >= 4) { A = A2; W = W2; wld = wld2; k0 = (kc - 4) * 128; }
  else                 { A = A1; W = W1; wld = wld1; k0 = kc * 128; }
  __shared__ float Ask[64][68];
  __shared__ float Ws[64][68];
  int tid = threadIdx.x;
  int bq = tid >> 4, nq = tid & 15;
  int b0 = bq * 4, n0 = nq * 4;
  float acc[4][4] = {};
  for (int kb = 0; kb < 128; kb += 64) {
    {
      int brow = tid & 63;
      int kcb = (tid >> 6) * 16;
      const float* ap = A + (size_t)brow * 512 + k0 + kb + kcb;
      #pragma unroll
      for (int j = 0; j < 4; j++) {
        float4 a4 = *(const float4*)(ap + j * 4);
        Ask[kcb + j * 4 + 0][brow] = a4.x;
        Ask[kcb + j * 4 + 1][brow] = a4.y;
        Ask[kcb + j * 4 + 2][brow] = a4.z;
        Ask[kcb + j * 4 + 3][brow] = a4.w;
      }
      int nc = (tid & 15) * 4;
      #pragma unroll
      for (int j = 0; j < 4; j++) {
        int krow = (tid >> 4) + j * 16;
        *(float4*)&Ws[krow][nc] =
            *(const float4*)&W[(size_t)(k0 + kb + krow) * wld + nt * 64 + nc];
      }
    }
    __syncthreads();
    #pragma unroll
    for (int kk = 0; kk < 64; kk++) {
      float4 a = *(float4*)&Ask[kk][b0];
      float4 w = *(float4*)&Ws[kk][n0];
      acc[0][0] += a.x * w.x; acc[0][1] += a.x * w.y; acc[0][2] += a.x * w.z; acc[0][3] += a.x * w.w;
      acc[1][0] += a.y * w.x; acc[1][1] += a.y * w.y; acc[1][2] += a.y * w.z; acc[1][3] += a.y * w.w;
      acc[2][0] += a.z * w.x; acc[2][1] += a.z * w.y; acc[2][2] += a.z * w.z; acc[2][3] += a.z * w.w;
      acc[3][0] += a.w * w.x; acc[3][1] += a.w * w.y; acc[3][2] += a.w * w.z; acc[3][3] += a.w * w.w;
    }
    __syncthreads();
  }
  float* Cout = Cpart + (size_t)kc * BB * N + (size_t)nt * 64;
  #pragma unroll
  for (int i = 0; i < 4; i++) {
    float4 v = make_float4(acc[i][0], acc[i][1], acc[i][2], acc[i][3]);
    *(float4*)&Cout[(size_t)(b0 + i) * N + n0] = v;
  }
}

// ---------------- attention: per (batch, chunk of 128 rows), one-pass online softmax ----------------
__global__ __launch_bounds__(256) void attn_k(const float* __restrict__ hp,
    const float* __restrict__ qpart, const float* __restrict__ phi_b,
    float* __restrict__ partm, float* __restrict__ partl, float* __restrict__ partacc) {
  int b = blockIdx.x >> 3, ch = blockIdx.x & 7;
  __shared__ float qs[HH];
  __shared__ float wacc[4][HH];
  __shared__ float wml[8];
  int tid = threadIdx.x;
  for (int d = tid; d < HH; d += 256) {
    float v = phi_b[d];
    #pragma unroll
    for (int p = 0; p < 4; p++) v += qpart[((size_t)p * BB + b) * HH + d];
    qs[d] = v;
  }
  __syncthreads();
  int wave = tid >> 6, lane = tid & 63;
  float qreg[8];
  {
    const float* qp = qs + lane * 8;
    #pragma unroll
    for (int j = 0; j < 8; j++) qreg[j] = qp[j];
  }
  float m = -INFINITY, l = 0.f;
  float acc[8] = {0, 0, 0, 0, 0, 0, 0, 0};
  const float* hpb = hp + ((size_t)b * RR + ch * 128 + wave * 32) * HH + lane * 8;
  float4 v0 = *(const float4*)hpb;
  float4 v1 = *(const float4*)(hpb + 4);
  for (int i = 0; i < 32; i++) {
    float4 n0v, n1v;
    if (i < 31) {
      n0v = *(const float4*)(hpb + (size_t)(i + 1) * HH);
      n1v = *(const float4*)(hpb + (size_t)(i + 1) * HH + 4);
    }
    float rv[8] = {v0.x, v0.y, v0.z, v0.w, v1.x, v1.y, v1.z, v1.w};
    float d0 = 0.f;
    #pragma unroll
    for (int j = 0; j < 8; j++) d0 += qreg[j] * rv[j];
    #pragma unroll
    for (int off = 32; off > 0; off >>= 1) d0 += __shfl_xor(d0, off, 64);
    float mn = fmaxf(m, d0);
    float sc = __expf(m - mn);
    float w = __expf(d0 - mn);
    l = l * sc + w;
    #pragma unroll
    for (int j = 0; j < 8; j++) acc[j] = acc[j] * sc + w * rv[j];
    m = mn;
    v0 = n0v; v1 = n1v;
  }
  #pragma unroll
  for (int j = 0; j < 8; j++) wacc[wave][lane * 8 + j] = acc[j];
  if (lane == 0) { wml[wave] = m; wml[4 + wave] = l; }
  __syncthreads();
  float M = fmaxf(fmaxf(wml[0], wml[1]), fmaxf(wml[2], wml[3]));
  float e0 = __expf(wml[0] - M), e1 = __expf(wml[1] - M);
  float e2 = __expf(wml[2] - M), e3 = __expf(wml[3] - M);
  if (tid == 0) {
    partm[b * 8 + ch] = M;
    partl[b * 8 + ch] = wml[4] * e0 + wml[5] * e1 + wml[6] * e2 + wml[7] * e3;
  }
  for (int d = tid; d < HH; d += 256) {
    partacc[((size_t)b * 8 + ch) * HH + d] =
        wacc[0][d] * e0 + wacc[1][d] * e1 + wacc[2][d] * e2 + wacc[3][d] * e3;
  }
}

// ---------------- combine the 8 chunk-partials into context c[64][512] ----------------
__global__ __launch_bounds__(256) void combine_k(const float* __restrict__ partm,
    const float* __restrict__ partl, const float* __restrict__ partacc,
    float* __restrict__ cbuf) {
  int b = blockIdx.x, tid = threadIdx.x;
  float M = -INFINITY;
  #pragma unroll
  for (int p = 0; p < 8; p++) M = fmaxf(M, partm[b * 8 + p]);
  float sc[8]; float L = 0.f;
  #pragma unroll
  for (int p = 0; p < 8; p++) { sc[p] = __expf(partm[b * 8 + p] - M); L += sc[p] * partl[b * 8 + p]; }
  float inv = 1.f / L;
  for (int d = tid; d < HH; d += 256) {
    float v = 0.f;
    #pragma unroll
    for (int p = 0; p < 8; p++) v += sc[p] * partacc[((size_t)b * 8 + p) * HH + d];
    cbuf[b * HH + d] = v * inv;
  }
}

// ---------------- LSTM cell 0 pointwise (+ gate-partial reduce + one-hot gather) ----------------
__global__ __launch_bounds__(256) void act0_k(const float* __restrict__ gpart,
    const float* __restrict__ b_ih, const float* __restrict__ b_hh,
    const float* __restrict__ wyT, const int* __restrict__ y, int t,
    float* __restrict__ s0, float* __restrict__ cs0) {
  int idx = blockIdx.x * 256 + threadIdx.x;
  int b = idx >> 9, jj = idx & 511;
  int yv = y[b * TT + t];
  float g[4];
  #pragma unroll
  for (int gi = 0; gi < 4; gi++) {
    int j = gi * 512 + jj;
    float v = b_ih[j] + b_hh[j] + wyT[(size_t)yv * GG + j];
    #pragma unroll
    for (int p = 0; p < 8; p++) v += gpart[((size_t)p * BB + b) * GG + j];
    g[gi] = v;
  }
  float cn = sigmf(g[1]) * cs0[idx] + sigmf(g[0]) * tanhf(g[2]);
  cs0[idx] = cn;
  s0[idx] = sigmf(g[3]) * tanhf(cn);
}

// ---------------- LSTM cell 1 pointwise (+ reduce) ; writes s_seq ----------------
__global__ __launch_bounds__(256) void act1_k(const float* __restrict__ gpart,
    const float* __restrict__ b_ih, const float* __restrict__ b_hh,
    int t, float* __restrict__ s1, float* __restrict__ cs1, float* __restrict__ s_seq) {
  int idx = blockIdx.x * 256 + threadIdx.x;
  int b = idx >> 9, jj = idx & 511;
  float g[4];
  #pragma unroll
  for (int gi = 0; gi < 4; gi++) {
    int j = gi * 512 + jj;
    float v = b_ih[j] + b_hh[j];
    #pragma unroll
    for (int p = 0; p < 8; p++) v += gpart[((size_t)p * BB + b) * GG + j];
    g[gi] = v;
  }
  float cn = sigmf(g[1]) * cs1[idx] + sigmf(g[0]) * tanhf(g[2]);
  cs1[idx] = cn;
  float h = sigmf(g[3]) * tanhf(cn);
  s1[idx] = h;
  s_seq[((size_t)b * TT + t) * HH + jj] = h;
}

extern "C" void kernel_launch(void* const* d_in, const int* in_sizes, int n_in,
                              void* d_out, int out_size, void* d_ws, size_t ws_size,
                              hipStream_t stream) {
  (void)in_sizes; (void)n_in; (void)out_size; (void)ws_size;
  const float* h     = (const float*)d_in[0];
  const int*   y     = (const int*)d_in[1];
  const float* phi_w = (const float*)d_in[2];
  const float* phi_b = (const float*)d_in[3];
  const float* psi_w = (const float*)d_in[4];
  const float* psi_b = (const float*)d_in[5];
  const float* w_ih0 = (const float*)d_in[6];
  const float* w_hh0 = (const float*)d_in[7];
  const float* b_ih0 = (const float*)d_in[8];
  const float* b_hh0 = (const float*)d_in[9];
  const float* w_ih1 = (const float*)d_in[10];
  const float* w_hh1 = (const float*)d_in[11];
  const float* b_ih1 = (const float*)d_in[12];
  const float* b_hh1 = (const float*)d_in[13];
  const float* out_w = (const float*)d_in[14];
  const float* out_b = (const float*)d_in[15];
  float* out = (float*)d_out;

  float* ws = (float*)d_ws;
  size_t off = 0;
  auto alloc = [&](size_t n) { size_t o = off; off += (n + 63) & ~(size_t)63; return o; };
  float* hp     = ws + alloc((size_t)BB * RR * HH);   // 128 MB
  float* psi_wT = ws + alloc(HH * HH);
  float* phi_wT = ws + alloc(HH * HH);
  float* wc0T   = ws + alloc(HH * GG);
  float* whh0T  = ws + alloc(HH * GG);
  float* wih1T  = ws + alloc(HH * GG);
  float* whh1T  = ws + alloc(HH * GG);
  float* wyT    = ws + alloc((size_t)VV * GG);
  float* out_wT = ws + alloc((size_t)HH * 1024);      // padded [512][1024]
  float* st     = ws + alloc(4 * BB * HH);
  float* s0 = st, *cs0 = st + BB * HH, *s1 = st + 2 * BB * HH, *cs1 = st + 3 * BB * HH;
  float* qpart  = ws + alloc(4 * BB * HH);
  float* cbuf   = ws + alloc(BB * HH);
  float* g0part = ws + alloc((size_t)8 * BB * GG);
  float* g1part = ws + alloc((size_t)8 * BB * GG);
  float* partm  = ws + alloc(BB * 8);
  float* partl  = ws + alloc(BB * 8);
  float* partacc= ws + alloc((size_t)BB * 8 * HH);
  float* s_seq  = ws + alloc((size_t)BB * TT * HH);

  // zero the recurrent states (deterministic start every call)
  hipMemsetAsync(st, 0, (size_t)4 * BB * HH * sizeof(float), stream);

  dim3 tb(256);
  // weight transposes (K-major layouts)
  transpose_k<<<dim3(16, 16), tb, 0, stream>>>(psi_w, psi_wT, 512, 512, 512, 512, 0);
  transpose_k<<<dim3(16, 16), tb, 0, stream>>>(phi_w, phi_wT, 512, 512, 512, 512, 0);
  transpose_k<<<dim3(16, 64), tb, 0, stream>>>(w_ih0, wc0T, 2048, 2048, 512, 1512, 1000);
  transpose_k<<<dim3(16, 64), tb, 0, stream>>>(w_hh0, whh0T, 2048, 2048, 512, 512, 0);
  transpose_k<<<dim3(16, 64), tb, 0, stream>>>(w_ih1, wih1T, 2048, 2048, 512, 512, 0);
  transpose_k<<<dim3(16, 64), tb, 0, stream>>>(w_hh1, whh1T, 2048, 2048, 512, 512, 0);
  transpose_k<<<dim3(32, 64), tb, 0, stream>>>(w_ih0, wyT, 2048, 2048, 1000, 1512, 0);
  transpose_k<<<dim3(16, 32), tb, 0, stream>>>(out_w, out_wT, 1000, 1024, 512, 512, 0);

  // hp = h @ psi_w.T + psi_b   [65536, 512]
  biggemm_k<<<dim3(512, 8), tb, 0, stream>>>(h, psi_wT, 512, psi_b, hp, 512, 512);

  for (int t = 0; t < TT; t++) {
    // q partials: s1 @ phi_w.T (bias added inside attn)
    smallgemm_k<<<dim3(8, 4), tb, 0, stream>>>(s1, phi_wT, 512, s1, phi_wT, 512, 0, qpart, 512);
    // one-pass online-softmax attention over hp
    attn_k<<<dim3(512), tb, 0, stream>>>(hp, qpart, phi_b, partm, partl, partacc);
    combine_k<<<dim3(64), tb, 0, stream>>>(partm, partl, partacc, cbuf);
    // LSTM0 gates: c @ w_ih0[:,1000:].T + s0 @ w_hh0.T
    smallgemm_k<<<dim3(32, 8), tb, 0, stream>>>(cbuf, wc0T, 2048, s0, whh0T, 2048, 1, g0part, 2048);
    act0_k<<<dim3(128), tb, 0, stream>>>(g0part, b_ih0, b_hh0, wyT, y, t, s0, cs0);
    // LSTM1 gates: s0 @ w_ih1.T + s1 @ w_hh1.T
    smallgemm_k<<<dim3(32, 8), tb, 0, stream>>>(s0, wih1T, 2048, s1, whh1T, 2048, 1, g1part, 2048);
    act1_k<<<dim3(128), tb, 0, stream>>>(g1part, b_ih1, b_hh1, t, s1, cs1, s_seq);
  }

  // out = s_seq @ out_w.T + out_b   [12800, 1000]
  biggemm_k<<<dim3(100, 16), tb, 0, stream>>>(s_seq, out_wT, 1024, out_b, out, 1000, 1000);
}